// Round 12
// baseline (121.312 us; speedup 1.0000x reference)
//
#include <hip/hip_runtime.h>

typedef __attribute__((ext_vector_type(8))) short short8;
typedef __attribute__((ext_vector_type(4))) float f32x4;
typedef unsigned short ushort_t;

#define N_OSC   256
#define NUM_CN  32
#define BATCH   64
#define T_STEPS 40
#define DT      0.125f

#define GK      8192
#define GN      8192
#define BN      64
#define KSPLIT  8
#define KRANGE  1024          // GK / KSPLIT
#define BK      64            // k-rows per chunk
#define NCHUNK  16            // KRANGE / BK
#define PH_ELEMS 655360       // 40*64*256

__device__ __forceinline__ unsigned short f2bf(float f) {
    unsigned u = __float_as_uint(f);
    return (unsigned short)((u + 0x7fffu + ((u >> 16) & 1u)) >> 16);
}

__device__ __forceinline__ void stage16(const void* g, void* l) {
    __builtin_amdgcn_global_load_lds(
        (const __attribute__((address_space(1))) void*)g,
        (__attribute__((address_space(3))) void*)l, 16, 0, 0);
}

// ---------------- Kernel 1: conv stack -> feat (bf16) [proven] --------------
__global__ __launch_bounds__(256) void conv_kernel(
    const float* __restrict__ x,  const float* __restrict__ w0,
    const float* __restrict__ b0, const float* __restrict__ w1,
    const float* __restrict__ b1, ushort_t* __restrict__ featB)
{
    __shared__ float xs[3][256];
    __shared__ float h0[16][256];
    int blk = blockIdx.x;
    int b = blk >> 2, og = blk & 3;
    int p = threadIdx.x;
    int y = p >> 4, x0 = p & 15;

    #pragma unroll
    for (int c = 0; c < 3; ++c) xs[c][p] = x[b * 768 + c * 256 + p];
    __syncthreads();

    float acc0[16];
    #pragma unroll
    for (int o = 0; o < 16; ++o) acc0[o] = b0[o];
    #pragma unroll
    for (int c = 0; c < 3; ++c)
        #pragma unroll
        for (int ky = 0; ky < 3; ++ky) {
            int yy = y + ky - 1;
            if (yy < 0 || yy > 15) continue;
            #pragma unroll
            for (int kx = 0; kx < 3; ++kx) {
                int xx = x0 + kx - 1;
                if (xx < 0 || xx > 15) continue;
                float v = xs[c][yy * 16 + xx];
                #pragma unroll
                for (int o = 0; o < 16; ++o)
                    acc0[o] = fmaf(v, w0[o * 27 + c * 9 + ky * 3 + kx], acc0[o]);
            }
        }
    #pragma unroll
    for (int o = 0; o < 16; ++o) h0[o][p] = tanhf(acc0[o]);
    __syncthreads();

    float acc1[8];
    #pragma unroll
    for (int o = 0; o < 8; ++o) acc1[o] = b1[og * 8 + o];
    for (int c = 0; c < 16; ++c)
        #pragma unroll
        for (int ky = 0; ky < 3; ++ky) {
            int yy = y + ky - 1;
            if (yy < 0 || yy > 15) continue;
            #pragma unroll
            for (int kx = 0; kx < 3; ++kx) {
                int xx = x0 + kx - 1;
                if (xx < 0 || xx > 15) continue;
                float v = h0[c][yy * 16 + xx];
                #pragma unroll
                for (int o = 0; o < 8; ++o)
                    acc1[o] = fmaf(v, w1[(og * 8 + o) * 144 + c * 9 + ky * 3 + kx], acc1[o]);
            }
        }
    #pragma unroll
    for (int o = 0; o < 8; ++o)
        featB[b * 8192 + (og * 8 + o) * 256 + p] = f2bf(tanhf(acc1[o]));
}

// ---------------- Kernel 2: GEMM (M-split waves) [proven, ~48us = 89% BW] ---
__global__ __launch_bounds__(256, 4) void gemm_kernel(
    const ushort_t* __restrict__ featB,
    const float*    __restrict__ lin_w,
    float*          __restrict__ partials)
{
    __shared__ float ldsB[2][4096];
    int tid  = threadIdx.x;
    int lane = tid & 63, wid = tid >> 6;
    int l15  = lane & 15;
    int kg   = lane >> 4;
    int n0   = blockIdx.x * BN;
    int k0   = blockIdx.y * KRANGE;

    int st_kb = tid >> 4;
    int st_cp = (tid & 15) * 4;

    f32x4 acc[4];
    #pragma unroll
    for (int nf = 0; nf < 4; ++nf) acc[nf] = (f32x4){0.f, 0.f, 0.f, 0.f};

    const float* gb = lin_w + (size_t)k0 * GN + n0;

    #pragma unroll
    for (int i = 0; i < 4; ++i) {
        int k = i * 16 + st_kb;
        int c0 = st_cp ^ (((k >> 3) & 3) << 4);
        stage16(gb + (size_t)k * GN + c0, &ldsB[0][ i * 1024 + wid * 256 ]);
    }

    int arow = wid * 16 + l15;
    const ushort_t* abase = featB + (size_t)arow * GK + k0 + kg * 8;

    #pragma unroll 2
    for (int c = 0; c < NCHUNK; ++c) {
        int cur = c & 1;
        __syncthreads();
        if (c + 1 < NCHUNK) {
            const float* gn = gb + (size_t)(c + 1) * BK * GN;
            #pragma unroll
            for (int i = 0; i < 4; ++i) {
                int k = i * 16 + st_kb;
                int c0 = st_cp ^ (((k >> 3) & 3) << 4);
                stage16(gn + (size_t)k * GN + c0, &ldsB[cur ^ 1][ i * 1024 + wid * 256 ]);
            }
        }
        #pragma unroll
        for (int kk = 0; kk < 2; ++kk) {
            short8 af = *(const short8*)(abase + c * BK + kk * 32);
            #pragma unroll
            for (int nf = 0; nf < 4; ++nf) {
                int colswz = (nf * 16 + l15) ^ (kg << 4);
                const float* bsrc = &ldsB[cur][(kk * 32 + kg * 8) * 64 + colswz];
                short8 bfrag;
                #pragma unroll
                for (int i = 0; i < 8; ++i)
                    bfrag[i] = (short)f2bf(bsrc[i * 64]);
                acc[nf] = __builtin_amdgcn_mfma_f32_16x16x32_bf16(af, bfrag, acc[nf], 0, 0, 0);
            }
        }
    }

    float* pout = partials + (size_t)blockIdx.y * (64 * GN) + n0;
    int r4 = (lane >> 4) * 4;
    #pragma unroll
    for (int nf = 0; nf < 4; ++nf)
        #pragma unroll
        for (int r = 0; r < 4; ++r)
            pout[(size_t)(wid * 16 + r4 + r) * GN + nf * 16 + l15] = acc[nf][r];
}

// ---------------- Kernel 3: fused reduce+norm+scatter (4096 blocks) [proven] -
__global__ __launch_bounds__(256) void rns_kernel(
    const float* __restrict__ partials, const float* __restrict__ lin_b,
    const int* __restrict__ conn, float* __restrict__ cpl,
    float* __restrict__ ncount, float* __restrict__ Kout)
{
    __shared__ float rows[4][256];
    int lane = threadIdx.x & 63, wid = threadIdx.x >> 6;
    int ridx = blockIdx.x * 4 + wid;      // b*256 + n
    int n = ridx & 255, b = ridx >> 8;
    int k = lane & 31;
    int yh = (lane >> 5) * 4;

    float c = 0.f;
    const float* pp = partials + (size_t)b * GN + n * 32 + k;
    #pragma unroll
    for (int y = 0; y < 4; ++y)
        c += pp[(size_t)(yh + y) * (64 * GN)];
    c += __shfl_down(c, 32);
    c += lin_b[n * 32 + k];

    float sq = (lane < 32) ? c * c : 0.f;
    #pragma unroll
    for (int off = 1; off < 64; off <<= 1) sq += __shfl_xor(sq, off);
    float inv = 1.0f / sqrtf(sq);
    float val = c * inv;

    if (lane < 32) cpl[(size_t)ridx * 32 + k] = val;

    *(float4*)&rows[wid][lane * 4] = (float4){0.f, 0.f, 0.f, 0.f};
    __syncthreads();
    if (lane < 32) atomicAdd(&rows[wid][conn[n * 32 + k]], val);
    __syncthreads();
    float4 vv = *(float4*)&rows[wid][lane * 4];
    int cnt = (vv.x != 0.f) + (vv.y != 0.f) + (vv.z != 0.f) + (vv.w != 0.f);
    #pragma unroll
    for (int off = 32; off; off >>= 1) cnt += __shfl_down(cnt, off);
    *(float4*)&Kout[(size_t)ridx * 256 + lane * 4] = vv;
    if (lane == 0) ncount[ridx] = (float)cnt;
}

// ---------------- Kernel 4: Kuramoto Euler, 512 thr (split gathers) ---------
// Pair (h=0,h=1) shares oscillator n: each gathers 16 couplings; h=1's partial
// crosses via pS/pC (every LDS write->read crosses a barrier — r10 lesson).
// sc double-buffered: iter t writes sc[t&1], so no WAR on the buffer being
// read (writes to sc[cur^1] happen after the barrier ending iter t's reads).
__global__ __launch_bounds__(512) void ode_kernel(
    const float* __restrict__ cpl, const int* __restrict__ conn,
    const float* __restrict__ ncount, const float* __restrict__ phase0,
    float* __restrict__ phases)
{
    __shared__ float2 sc[2][256];
    __shared__ float  pS[256], pC[256];
    int b = blockIdx.x;
    int h = threadIdx.x >> 8, n = threadIdx.x & 255;
    float w[16]; int j[16];
    #pragma unroll
    for (int q = 0; q < 16; ++q) {
        w[q] = cpl[(size_t)(b * 256 + n) * 32 + h * 16 + q];
        j[q] = conn[n * 32 + h * 16 + q];
    }
    float ph = 0.f, inv = 0.f;
    if (h == 0) {
        ph  = phase0[b * 256 + n];
        inv = 1.0f / ncount[b * 256 + n];
    }
    float* out = phases + b * 256 + n;
    for (int t = 0; t < T_STEPS; ++t) {
        int cur = t & 1;
        float s = 0.f, cc = 0.f;
        if (h == 0) {
            __sincosf(ph, &s, &cc);
            sc[cur][n] = make_float2(s, cc);
        }
        __syncthreads();
        float aS = 0.f, aC = 0.f;
        #pragma unroll
        for (int q = 0; q < 16; ++q) {
            float2 v = sc[cur][j[q]];
            aS = fmaf(w[q], v.x, aS);
            aC = fmaf(w[q], v.y, aC);
        }
        if (h == 1) { pS[n] = aS; pC[n] = aC; }
        __syncthreads();
        if (h == 0) {
            aS += pS[n]; aC += pC[n];
            ph += DT * (aS * cc - aC * s) * inv;
            out[t * (BATCH * N_OSC)] = ph;
        }
    }
}

extern "C" void kernel_launch(void* const* d_in, const int* in_sizes, int n_in,
                              void* d_out, int out_size, void* d_ws, size_t ws_size,
                              hipStream_t stream) {
    const float* x      = (const float*)d_in[0];
    const float* w0     = (const float*)d_in[1];
    const float* b0     = (const float*)d_in[2];
    const float* w1     = (const float*)d_in[3];
    const float* b1     = (const float*)d_in[4];
    const float* lin_w  = (const float*)d_in[5];
    const float* lin_b  = (const float*)d_in[6];
    const int*   conn   = (const int*)d_in[7];
    const float* phase0 = (const float*)d_in[8];

    float* out    = (float*)d_out;
    float* phases = out;                 // [40][64][256]
    float* Kout   = out + PH_ELEMS;      // [64][256][256]

    char* ws = (char*)d_ws;
    ushort_t* featB    = (ushort_t*)ws;                // 1 MB @ 0
    float*    cpl      = (float*)(ws + (1 << 20));     // 2 MB @ 1M
    float*    ncount   = (float*)(ws + (3 << 20));     // 64 KB @ 3M
    float*    partials = (float*)(ws + (4 << 20));     // 16 MB @ 4M

    conv_kernel<<<dim3(256), dim3(256), 0, stream>>>(x, w0, b0, w1, b1, featB);
    gemm_kernel<<<dim3(GN / BN, KSPLIT), dim3(256), 0, stream>>>(featB, lin_w, partials);
    rns_kernel<<<dim3(4096), dim3(256), 0, stream>>>(partials, lin_b, conn,
                                                     cpl, ncount, Kout);
    ode_kernel<<<dim3(64), dim3(512), 0, stream>>>(cpl, conn, ncount, phase0, phases);
}

// Round 13
// 116.980 us; speedup vs baseline: 1.0370x; 1.0370x over previous
//
#include <hip/hip_runtime.h>

typedef __attribute__((ext_vector_type(8))) short short8;
typedef __attribute__((ext_vector_type(4))) float f32x4;
typedef unsigned short ushort_t;

#define N_OSC   256
#define NUM_CN  32
#define BATCH   64
#define T_STEPS 40
#define DT      0.125f

#define GK      8192
#define GN      8192
#define BN      64
#define KSPLIT  8
#define KRANGE  1024          // GK / KSPLIT
#define BK      64            // k-rows per chunk
#define NCHUNK  16            // KRANGE / BK
#define PH_ELEMS 655360       // 40*64*256

__device__ __forceinline__ unsigned short f2bf(float f) {
    unsigned u = __float_as_uint(f);
    return (unsigned short)((u + 0x7fffu + ((u >> 16) & 1u)) >> 16);
}

__device__ __forceinline__ void stage16(const void* g, void* l) {
    __builtin_amdgcn_global_load_lds(
        (const __attribute__((address_space(1))) void*)g,
        (__attribute__((address_space(3))) void*)l, 16, 0, 0);
}

// ---------------- Kernel 1: conv stack -> feat (bf16) [proven] --------------
__global__ __launch_bounds__(256) void conv_kernel(
    const float* __restrict__ x,  const float* __restrict__ w0,
    const float* __restrict__ b0, const float* __restrict__ w1,
    const float* __restrict__ b1, ushort_t* __restrict__ featB)
{
    __shared__ float xs[3][256];
    __shared__ float h0[16][256];
    int blk = blockIdx.x;
    int b = blk >> 2, og = blk & 3;
    int p = threadIdx.x;
    int y = p >> 4, x0 = p & 15;

    #pragma unroll
    for (int c = 0; c < 3; ++c) xs[c][p] = x[b * 768 + c * 256 + p];
    __syncthreads();

    float acc0[16];
    #pragma unroll
    for (int o = 0; o < 16; ++o) acc0[o] = b0[o];
    #pragma unroll
    for (int c = 0; c < 3; ++c)
        #pragma unroll
        for (int ky = 0; ky < 3; ++ky) {
            int yy = y + ky - 1;
            if (yy < 0 || yy > 15) continue;
            #pragma unroll
            for (int kx = 0; kx < 3; ++kx) {
                int xx = x0 + kx - 1;
                if (xx < 0 || xx > 15) continue;
                float v = xs[c][yy * 16 + xx];
                #pragma unroll
                for (int o = 0; o < 16; ++o)
                    acc0[o] = fmaf(v, w0[o * 27 + c * 9 + ky * 3 + kx], acc0[o]);
            }
        }
    #pragma unroll
    for (int o = 0; o < 16; ++o) h0[o][p] = tanhf(acc0[o]);
    __syncthreads();

    float acc1[8];
    #pragma unroll
    for (int o = 0; o < 8; ++o) acc1[o] = b1[og * 8 + o];
    for (int c = 0; c < 16; ++c)
        #pragma unroll
        for (int ky = 0; ky < 3; ++ky) {
            int yy = y + ky - 1;
            if (yy < 0 || yy > 15) continue;
            #pragma unroll
            for (int kx = 0; kx < 3; ++kx) {
                int xx = x0 + kx - 1;
                if (xx < 0 || xx > 15) continue;
                float v = h0[c][yy * 16 + xx];
                #pragma unroll
                for (int o = 0; o < 8; ++o)
                    acc1[o] = fmaf(v, w1[(og * 8 + o) * 144 + c * 9 + ky * 3 + kx], acc1[o]);
            }
        }
    #pragma unroll
    for (int o = 0; o < 8; ++o)
        featB[b * 8192 + (og * 8 + o) * 256 + p] = f2bf(tanhf(acc1[o]));
}

// ---------------- Kernel 2: GEMM (M-split waves) [proven, ~48us = 89% BW] ---
__global__ __launch_bounds__(256, 4) void gemm_kernel(
    const ushort_t* __restrict__ featB,
    const float*    __restrict__ lin_w,
    float*          __restrict__ partials)
{
    __shared__ float ldsB[2][4096];
    int tid  = threadIdx.x;
    int lane = tid & 63, wid = tid >> 6;
    int l15  = lane & 15;
    int kg   = lane >> 4;
    int n0   = blockIdx.x * BN;
    int k0   = blockIdx.y * KRANGE;

    int st_kb = tid >> 4;
    int st_cp = (tid & 15) * 4;

    f32x4 acc[4];
    #pragma unroll
    for (int nf = 0; nf < 4; ++nf) acc[nf] = (f32x4){0.f, 0.f, 0.f, 0.f};

    const float* gb = lin_w + (size_t)k0 * GN + n0;

    #pragma unroll
    for (int i = 0; i < 4; ++i) {
        int k = i * 16 + st_kb;
        int c0 = st_cp ^ (((k >> 3) & 3) << 4);
        stage16(gb + (size_t)k * GN + c0, &ldsB[0][ i * 1024 + wid * 256 ]);
    }

    int arow = wid * 16 + l15;
    const ushort_t* abase = featB + (size_t)arow * GK + k0 + kg * 8;

    #pragma unroll 2
    for (int c = 0; c < NCHUNK; ++c) {
        int cur = c & 1;
        __syncthreads();
        if (c + 1 < NCHUNK) {
            const float* gn = gb + (size_t)(c + 1) * BK * GN;
            #pragma unroll
            for (int i = 0; i < 4; ++i) {
                int k = i * 16 + st_kb;
                int c0 = st_cp ^ (((k >> 3) & 3) << 4);
                stage16(gn + (size_t)k * GN + c0, &ldsB[cur ^ 1][ i * 1024 + wid * 256 ]);
            }
        }
        #pragma unroll
        for (int kk = 0; kk < 2; ++kk) {
            short8 af = *(const short8*)(abase + c * BK + kk * 32);
            #pragma unroll
            for (int nf = 0; nf < 4; ++nf) {
                int colswz = (nf * 16 + l15) ^ (kg << 4);
                const float* bsrc = &ldsB[cur][(kk * 32 + kg * 8) * 64 + colswz];
                short8 bfrag;
                #pragma unroll
                for (int i = 0; i < 8; ++i)
                    bfrag[i] = (short)f2bf(bsrc[i * 64]);
                acc[nf] = __builtin_amdgcn_mfma_f32_16x16x32_bf16(af, bfrag, acc[nf], 0, 0, 0);
            }
        }
    }

    float* pout = partials + (size_t)blockIdx.y * (64 * GN) + n0;
    int r4 = (lane >> 4) * 4;
    #pragma unroll
    for (int nf = 0; nf < 4; ++nf)
        #pragma unroll
        for (int r = 0; r < 4; ++r)
            pout[(size_t)(wid * 16 + r4 + r) * GN + nf * 16 + l15] = acc[nf][r];
}

// ---------------- Kernel 3: fused reduce+norm+scatter (4096 blocks) [proven] -
__global__ __launch_bounds__(256) void rns_kernel(
    const float* __restrict__ partials, const float* __restrict__ lin_b,
    const int* __restrict__ conn, float* __restrict__ cpl,
    float* __restrict__ ncount, float* __restrict__ Kout)
{
    __shared__ float rows[4][256];
    int lane = threadIdx.x & 63, wid = threadIdx.x >> 6;
    int ridx = blockIdx.x * 4 + wid;      // b*256 + n
    int n = ridx & 255, b = ridx >> 8;
    int k = lane & 31;
    int yh = (lane >> 5) * 4;

    float c = 0.f;
    const float* pp = partials + (size_t)b * GN + n * 32 + k;
    #pragma unroll
    for (int y = 0; y < 4; ++y)
        c += pp[(size_t)(yh + y) * (64 * GN)];
    c += __shfl_down(c, 32);
    c += lin_b[n * 32 + k];

    float sq = (lane < 32) ? c * c : 0.f;
    #pragma unroll
    for (int off = 1; off < 64; off <<= 1) sq += __shfl_xor(sq, off);
    float inv = 1.0f / sqrtf(sq);
    float val = c * inv;

    if (lane < 32) cpl[(size_t)ridx * 32 + k] = val;

    *(float4*)&rows[wid][lane * 4] = (float4){0.f, 0.f, 0.f, 0.f};
    __syncthreads();
    if (lane < 32) atomicAdd(&rows[wid][conn[n * 32 + k]], val);
    __syncthreads();
    float4 vv = *(float4*)&rows[wid][lane * 4];
    int cnt = (vv.x != 0.f) + (vv.y != 0.f) + (vv.z != 0.f) + (vv.w != 0.f);
    #pragma unroll
    for (int off = 32; off; off >>= 1) cnt += __shfl_down(cnt, off);
    *(float4*)&Kout[(size_t)ridx * 256 + lane * 4] = vv;
    if (lane == 0) ncount[ridx] = (float)cnt;
}

// ---------------- Kernel 4: Kuramoto Euler, 256 thr, 1 barrier/step ---------
// r6-proven body + double-buffered sc -> the trailing barrier is removable:
// iter t+1 writes buffer cur^1 (never read in iter t); reaching iter t+2's
// write of buffer cur requires passing barrier t+1, which orders it after
// all iter-t reads of that buffer. Every LDS write->read crosses a barrier.
__global__ __launch_bounds__(256) void ode_kernel(
    const float* __restrict__ cpl, const int* __restrict__ conn,
    const float* __restrict__ ncount, const float* __restrict__ phase0,
    float* __restrict__ phases)
{
    __shared__ float2 sc[2][256];
    int b = blockIdx.x, n = threadIdx.x;
    float w[32]; int j[32];
    #pragma unroll
    for (int k = 0; k < 32; ++k) {
        w[k] = cpl[(size_t)(b * 256 + n) * 32 + k];
        j[k] = conn[n * 32 + k];
    }
    float inv = 1.0f / ncount[b * 256 + n];
    float ph = phase0[b * 256 + n];
    float* out = phases + b * 256 + n;
    for (int t = 0; t < T_STEPS; ++t) {
        int cur = t & 1;
        float s, c;
        __sincosf(ph, &s, &c);
        sc[cur][n] = make_float2(s, c);
        __syncthreads();
        float aS = 0.f, aC = 0.f;
        #pragma unroll
        for (int k = 0; k < 32; ++k) {
            float2 v = sc[cur][j[k]];
            aS = fmaf(w[k], v.x, aS);
            aC = fmaf(w[k], v.y, aC);
        }
        ph += DT * (aS * c - aC * s) * inv;
        out[t * (BATCH * N_OSC)] = ph;
    }
}

extern "C" void kernel_launch(void* const* d_in, const int* in_sizes, int n_in,
                              void* d_out, int out_size, void* d_ws, size_t ws_size,
                              hipStream_t stream) {
    const float* x      = (const float*)d_in[0];
    const float* w0     = (const float*)d_in[1];
    const float* b0     = (const float*)d_in[2];
    const float* w1     = (const float*)d_in[3];
    const float* b1     = (const float*)d_in[4];
    const float* lin_w  = (const float*)d_in[5];
    const float* lin_b  = (const float*)d_in[6];
    const int*   conn   = (const int*)d_in[7];
    const float* phase0 = (const float*)d_in[8];

    float* out    = (float*)d_out;
    float* phases = out;                 // [40][64][256]
    float* Kout   = out + PH_ELEMS;      // [64][256][256]

    char* ws = (char*)d_ws;
    ushort_t* featB    = (ushort_t*)ws;                // 1 MB @ 0
    float*    cpl      = (float*)(ws + (1 << 20));     // 2 MB @ 1M
    float*    ncount   = (float*)(ws + (3 << 20));     // 64 KB @ 3M
    float*    partials = (float*)(ws + (4 << 20));     // 16 MB @ 4M

    conv_kernel<<<dim3(256), dim3(256), 0, stream>>>(x, w0, b0, w1, b1, featB);
    gemm_kernel<<<dim3(GN / BN, KSPLIT), dim3(256), 0, stream>>>(featB, lin_w, partials);
    rns_kernel<<<dim3(4096), dim3(256), 0, stream>>>(partials, lin_b, conn,
                                                     cpl, ncount, Kout);
    ode_kernel<<<dim3(64), dim3(256), 0, stream>>>(cpl, conn, ncount, phase0, phases);
}